// Round 18
// baseline (496.691 us; speedup 1.0000x reference)
//
#include <hip/hip_runtime.h>
#include <hip/hip_bf16.h>
#include <stdint.h>

#define T_DIM 4096
#define H_DIM 1024
#define I_DIM 2048
#define KCAT 4096  // concatenated K for gemm2 (2 experts x I_DIM)

typedef __bf16 bf16x8 __attribute__((ext_vector_type(8)));
typedef float f32x4 __attribute__((ext_vector_type(4)));
typedef unsigned short ushort_t;
typedef unsigned short us4 __attribute__((ext_vector_type(4)));
typedef unsigned short us8 __attribute__((ext_vector_type(8)));

__device__ __forceinline__ unsigned short f32_to_bf16(float f) {
  unsigned int u = __float_as_uint(f);
  u += 0x7fffu + ((u >> 16) & 1u);  // RNE
  return (unsigned short)(u >> 16);
}

__device__ __forceinline__ void gload_lds16(const void* g, void* l) {
  __builtin_amdgcn_global_load_lds(
      (__attribute__((address_space(1))) void*)(uintptr_t)g,
      (__attribute__((address_space(3))) void*)(unsigned int)(uintptr_t)l,
      16, 0, 0);
}

// XOR swizzle (involution; bits 4-6 ^= bits 7-9 of byte offset). Verified R4:
// SQ_LDS_BANK_CONFLICT 6.29M -> 0. Transparent to adds of multiples of 1024.
__device__ __forceinline__ int swz(int L) { return L ^ (((L >> 7) & 7) << 4); }

#define S_BARRIER() asm volatile("s_barrier" ::: "memory")
#define WAITV(n) asm volatile("s_waitcnt vmcnt(" #n ")" ::: "memory")
#define IRFENCE() asm volatile("" ::: "memory")
#define MFMA16(acc, va, vb) \
  acc = __builtin_amdgcn_mfma_f32_16x16x32_bf16(va, vb, acc, 0, 0, 0)

// ------- 64x64 transpose+convert: src f32 (stride sC) -> dst bf16 (stride dR) --
__device__ __forceinline__ void transpose_body64(const float* __restrict__ src,
                                                 ushort_t* __restrict__ dst,
                                                 int sC, int dR, int bx, int by,
                                                 float (*tile)[65]) {
  const int x0 = bx * 64, y0 = by * 64;
  const int tid = threadIdx.x;
  const int lcol4 = tid & 15, lrow = tid >> 4;
#pragma unroll
  for (int i = 0; i < 4; ++i) {
    const int r = lrow + 16 * i;
    const float4 v = ((const float4*)(src + (size_t)(y0 + r) * sC + x0))[lcol4];
    tile[r][lcol4 * 4 + 0] = v.x;
    tile[r][lcol4 * 4 + 1] = v.y;
    tile[r][lcol4 * 4 + 2] = v.z;
    tile[r][lcol4 * 4 + 3] = v.w;
  }
  __syncthreads();
  const int slotr = tid & 7, lcol = tid >> 3;  // 8 row-octs x 32 cols
#pragma unroll
  for (int i = 0; i < 2; ++i) {
    const int c = lcol + 32 * i;
    us8 o;
#pragma unroll
    for (int j = 0; j < 8; ++j) o[j] = f32_to_bf16(tile[slotr * 8 + j][c]);
    *(us8*)(dst + (size_t)(x0 + c) * dR + y0 + slotr * 8) = o;
  }
}

// ------- prep1: rmsnorm (blocks 0..T) + w1T (next 2048) + w2c (next 1024) ------
__global__ __launch_bounds__(256) void k_prep1(
    const float* __restrict__ x, const float* __restrict__ scale,
    const float* __restrict__ w1, const float* __restrict__ w2,
    ushort_t* __restrict__ normed, ushort_t* __restrict__ w1T,
    ushort_t* __restrict__ w2c) {
  __shared__ __align__(16) float shm[64][65];
  const int bid = blockIdx.x;
  if (bid < T_DIM) {
    const int row = bid, tid = threadIdx.x;
    const float4 v = ((const float4*)(x + (size_t)row * H_DIM))[tid];
    float ss = v.x * v.x + v.y * v.y + v.z * v.z + v.w * v.w;
#pragma unroll
    for (int off = 32; off > 0; off >>= 1) ss += __shfl_xor(ss, off);
    if ((tid & 63) == 0) shm[0][tid >> 6] = ss;
    __syncthreads();
    const float tot = shm[0][0] + shm[0][1] + shm[0][2] + shm[0][3];
    const float inv = rsqrtf(tot * (1.0f / H_DIM) + 1e-5f);
    const float4 sc = ((const float4*)scale)[tid];
    us4 o;
    o.x = f32_to_bf16(v.x * inv * sc.x);
    o.y = f32_to_bf16(v.y * inv * sc.y);
    o.z = f32_to_bf16(v.z * inv * sc.z);
    o.w = f32_to_bf16(v.w * inv * sc.w);
    ((us4*)(normed + (size_t)row * H_DIM))[tid] = o;
  } else if (bid < T_DIM + 2048) {
    // w1 [H][2I] -> w1T [2][2I][H]; grid (2I/64=64, H/64=16, 2) flattened.
    const int t = bid - T_DIM;
    const int e = t >> 10;
    transpose_body64(w1 + (size_t)e * H_DIM * 2 * I_DIM,
                     w1T + (size_t)e * 2 * I_DIM * H_DIM, 2 * I_DIM, H_DIM,
                     t & 63, (t >> 6) & 15, shm);
  } else {
    // w2 [I][H] -> w2c [H][KCAT] (expert e at col offset e*I);
    // grid (H/64=16, I/64=32, 2) flattened.
    const int t = bid - T_DIM - 2048;
    const int e = t >> 9;
    transpose_body64(w2 + (size_t)e * I_DIM * H_DIM, w2c + (size_t)e * I_DIM,
                     H_DIM, KCAT, t & 15, (t >> 4) & 31, shm);
  }
}

// ---------------- GEMM1: 128 x (128g+128l), BK=32, DBUF 48KB, 3 blocks/CU ------
// A/B vs R17 (tri-buffer 72KB, 2 blocks/CU): trade counted-vmcnt slack for
// +1 co-resident block (m114 inter-block overlap). Stage-1-ahead dbuf ->
// WAITV(0)+barrier per step. 4 waves 2x2, wave 64x(64g+64l).
__global__ __launch_bounds__(256, 3) void k_gemm1(
    const ushort_t* __restrict__ normed, const ushort_t* __restrict__ w1T,
    const float* __restrict__ b1, ushort_t* __restrict__ act) {
  __shared__ __align__(16) ushort_t lds[2][3][4096];  // 48 KiB
  char* const ldsB = (char*)&lds[0][0][0];
  const int tid = threadIdx.x;
  const int wg = ((blockIdx.x & 7) << 7) + (blockIdx.x >> 3);  // XCD swizzle
  const int e = wg >> 9;
  const int rem = wg & 511;
  const int brow = (rem >> 4) * 128;
  const int bcol = (rem & 15) * 128;
  const int lane = tid & 63;
  const int wid = tid >> 6;
  const int wm = wid >> 1, wn = wid & 1;
  const int r16 = lane & 15, kh = lane >> 4;

  const ushort_t* gBase = w1T + ((size_t)e * 2 * I_DIM + bcol) * H_DIM;
  const ushort_t* lBase = w1T + ((size_t)e * 2 * I_DIM + I_DIM + bcol) * H_DIM;

  f32x4 accg[4][4], accl[4][4];
  const f32x4 zf = {0.f, 0.f, 0.f, 0.f};
#pragma unroll
  for (int m = 0; m < 4; ++m)
#pragma unroll
    for (int n = 0; n < 4; ++n) { accg[m][n] = zf; accl[m][n] = zf; }

  const ushort_t* pA[2];
  const ushort_t* pG[2];
  const ushort_t* pL[2];
#pragma unroll
  for (int j = 0; j < 2; ++j) {
    const int u = swz(j * 4096 + tid * 16);
    const int r = u >> 6, c = (u & 63) >> 1;
    pA[j] = normed + (size_t)(brow + r) * H_DIM + c;
    pG[j] = gBase + (size_t)r * H_DIM + c;
    pL[j] = lBase + (size_t)r * H_DIM + c;
  }
  const int ldst0 = (tid & ~63) * 16;

  const int abase = swz((wm * 64 + r16) * 64 + kh * 16);
  const int bbase = 8192 + swz((wn * 64 + r16) * 64 + kh * 16);

  auto stage = [&](int buf) {
#pragma unroll
    for (int j = 0; j < 2; ++j) {
      gload_lds16(pA[j], ldsB + buf * 24576 + j * 4096 + ldst0);
      gload_lds16(pG[j], ldsB + buf * 24576 + 8192 + j * 4096 + ldst0);
      gload_lds16(pL[j], ldsB + buf * 24576 + 16384 + j * 4096 + ldst0);
    }
  };

  bf16x8 a[4], bg[4], bl[4];

#define G1_ADV()                                                              \
  {                                                                           \
    _Pragma("unroll") for (int j = 0; j < 2; ++j) {                           \
      pA[j] += 32; pG[j] += 32; pL[j] += 32;                                  \
    }                                                                         \
  }
#define G1_RD(C)                                                              \
  _Pragma("unroll") for (int m = 0; m < 4; ++m)                               \
      a[m] = *(const bf16x8*)(ldsB + (C) * 24576 + abase + m * 1024);         \
  _Pragma("unroll") for (int n = 0; n < 4; ++n) {                             \
    bg[n] = *(const bf16x8*)(ldsB + (C) * 24576 + bbase + n * 1024);          \
    bl[n] = *(const bf16x8*)(ldsB + (C) * 24576 + bbase + 8192 + n * 1024);   \
  }
#define G1_MFMA()                                                             \
  _Pragma("unroll") for (int m = 0; m < 4; ++m)                               \
      _Pragma("unroll") for (int n = 0; n < 4; ++n) {                         \
    MFMA16(accg[m][n], a[m], bg[n]);                                          \
    MFMA16(accl[m][n], a[m], bl[n]);                                          \
  }
// Step t (reading buf C): read frags, stage t+1 into the other buf, MFMA,
// drain all staging (WAITV(0)), barrier. WAR-safe: buf N's step-(t-1) reads
// completed before the t-1 barrier (compiler lgkmcnt precedes MFMA use).
#define G1_STEP(C, N)                                                         \
  {                                                                           \
    G1_RD(C);                                                                 \
    stage(N);                                                                 \
    __builtin_amdgcn_s_setprio(1);                                            \
    G1_MFMA();                                                                \
    __builtin_amdgcn_s_setprio(0);                                            \
    WAITV(0);                                                                 \
    S_BARRIER();                                                              \
    G1_ADV();                                                                 \
  }

  // Prologue: stage tile 0 into buf0.
  stage(0);
  G1_ADV();
  WAITV(0);
  S_BARRIER();

#pragma unroll 1
  for (int it = 0; it < 15; ++it) {  // steps t=0..29
    G1_STEP(0, 1);
    G1_STEP(1, 0);
  }
  G1_STEP(0, 1);  // t=30, stages t=31 into buf1
  // Tail: t=31 in buf1 (drained by t=30's WAITV(0)+barrier).
  {
    G1_RD(1);
    G1_MFMA();
  }
#undef G1_STEP
#undef G1_MFMA
#undef G1_RD
#undef G1_ADV

  const float* b1e = b1 + (size_t)e * 2 * I_DIM;
#pragma unroll
  for (int m = 0; m < 4; ++m)
#pragma unroll
    for (int n = 0; n < 4; ++n) {
      const int gcol = bcol + wn * 64 + n * 16 + r16;
      const float bgb = b1e[gcol];
      const float blb = b1e[I_DIM + gcol];
#pragma unroll
      for (int rr = 0; rr < 4; ++rr) {
        const int grow = brow + wm * 64 + m * 16 + kh * 4 + rr;
        const float hg = accg[m][n][rr] + bgb;
        const float hl = accl[m][n][rr] + blb;
        const float g = fminf(hg, 7.f);
        const float l = fminf(fmaxf(hl, -7.f), 7.f);
        const float s = 1.f / (1.f + __expf(-1.702f * g));
        const float av = g * s * (l + 1.f);
        act[(size_t)grow * KCAT + e * I_DIM + gcol] = f32_to_bf16(av);
      }
    }
}

// ---------------- GEMM2 (R17-verified): plain GEMM K=4096, 2-wave blocks -------
// Tile 128x64, 128 threads (2 waves), tri-buffer 36KB -> 4 blocks/CU,
// 6 loads/step, stage 2 ahead, WAITV(6)/step. 128 K-steps = 42x3 + 2 tail.
__global__ __launch_bounds__(128, 2) void k_gemm2(
    const ushort_t* __restrict__ act, const ushort_t* __restrict__ w2c,
    const float* __restrict__ x, const float* __restrict__ b2,
    float* __restrict__ out) {
  __shared__ __align__(16) ushort_t lds[3][6144];  // 36 KiB
  char* const ldsB = (char*)&lds[0][0];
  const int tid = threadIdx.x;
  const int wg = ((blockIdx.x & 7) << 6) + (blockIdx.x >> 3);  // XCD swizzle
  const int brow = (wg >> 4) * 128;
  const int bcol = (wg & 15) * 64;
  const int lane = tid & 63;
  const int wm = tid >> 6;
  const int r16 = lane & 15, kh = lane >> 4;

  const ushort_t* aBase = act + (size_t)brow * KCAT;
  const ushort_t* bBase = w2c + (size_t)bcol * KCAT;

  f32x4 acc[4][4];
  const f32x4 zf = {0.f, 0.f, 0.f, 0.f};
#pragma unroll
  for (int m = 0; m < 4; ++m)
#pragma unroll
    for (int n = 0; n < 4; ++n) acc[m][n] = zf;

  const ushort_t* pA[4];
  const ushort_t* pB[2];
#pragma unroll
  for (int j = 0; j < 4; ++j) {
    const int u = swz(j * 2048 + tid * 16);
    pA[j] = aBase + (size_t)(u >> 6) * KCAT + ((u & 63) >> 1);
  }
#pragma unroll
  for (int j = 0; j < 2; ++j) {
    const int u = swz(j * 2048 + tid * 16);
    pB[j] = bBase + (size_t)(u >> 6) * KCAT + ((u & 63) >> 1);
  }
  const int ldst0 = (tid & ~63) * 16;

  const int abase = wm * 4096 + swz(r16 * 64 + kh * 16);
  const int bbase = 8192 + swz(r16 * 64 + kh * 16);

  auto stage = [&](int buf) {
#pragma unroll
    for (int j = 0; j < 4; ++j)
      gload_lds16(pA[j], ldsB + buf * 12288 + j * 2048 + ldst0);
#pragma unroll
    for (int j = 0; j < 2; ++j)
      gload_lds16(pB[j], ldsB + buf * 12288 + 8192 + j * 2048 + ldst0);
  };

  bf16x8 a[4], b[4];

#define G2_ADV()                                                              \
  {                                                                           \
    _Pragma("unroll") for (int j = 0; j < 4; ++j) pA[j] += 32;                \
    _Pragma("unroll") for (int j = 0; j < 2; ++j) pB[j] += 32;                \
  }
#define G2_RD(C)                                                              \
  _Pragma("unroll") for (int m = 0; m < 4; ++m)                               \
      a[m] = *(const bf16x8*)(ldsB + (C) * 12288 + abase + m * 1024);         \
  _Pragma("unroll") for (int n = 0; n < 4; ++n)                               \
      b[n] = *(const bf16x8*)(ldsB + (C) * 12288 + bbase + n * 1024);
#define G2_MFMA()                                                             \
  _Pragma("unroll") for (int m = 0; m < 4; ++m)                               \
      _Pragma("unroll") for (int n = 0; n < 4; ++n)                           \
          MFMA16(acc[m][n], a[m], b[n]);
#define G2_STEP(C, N)                                                         \
  {                                                                           \
    G2_RD(C);                                                                 \
    stage(N);                                                                 \
    __builtin_amdgcn_s_setprio(1);                                            \
    G2_MFMA();                                                                \
    __builtin_amdgcn_s_setprio(0);                                            \
    WAITV(6);                                                                 \
    S_BARRIER();                                                              \
    G2_ADV();                                                                 \
  }

  stage(0); IRFENCE();
  G2_ADV();
  stage(1);
  G2_ADV();
  WAITV(6);
  S_BARRIER();

#pragma unroll 1
  for (int it = 0; it < 42; ++it) {  // steps t=0..125, staging t+2 (<=127)
    G2_STEP(0, 2);
    G2_STEP(1, 0);
    G2_STEP(2, 1);
  }
  // Tail: t=126 (b0), t=127 (b1; in flight).
  {
    G2_RD(0);
    G2_MFMA();
    WAITV(0);
    S_BARRIER();
    G2_RD(1);
    G2_MFMA();
  }
#undef G2_STEP
#undef G2_MFMA
#undef G2_RD
#undef G2_ADV

  // Epilogue: plain stores — out = x + 0.5*acc + 0.5*(b2[0]+b2[1]).
#pragma unroll
  for (int m = 0; m < 4; ++m)
#pragma unroll
    for (int n = 0; n < 4; ++n) {
      const int gcol = bcol + n * 16 + r16;
      const float bb = 0.5f * (b2[gcol] + b2[H_DIM + gcol]);
#pragma unroll
      for (int rr = 0; rr < 4; ++rr) {
        const int grow = brow + wm * 64 + m * 16 + kh * 4 + rr;
        out[(size_t)grow * H_DIM + gcol] =
            x[(size_t)grow * H_DIM + gcol] + 0.5f * acc[m][n][rr] + bb;
      }
    }
}

extern "C" void kernel_launch(void* const* d_in, const int* in_sizes, int n_in,
                              void* d_out, int out_size, void* d_ws, size_t ws_size,
                              hipStream_t stream) {
  const float* x = (const float*)d_in[0];
  const float* scale = (const float*)d_in[1];
  // d_in[2]=gate_kernel, d_in[3]=gate_bias: static routing, logits unused.
  const float* w1 = (const float*)d_in[4];
  const float* b1 = (const float*)d_in[5];
  const float* w2 = (const float*)d_in[6];
  const float* b2 = (const float*)d_in[7];
  float* out = (float*)d_out;

  ushort_t* ws = (ushort_t*)d_ws;
  ushort_t* normed = ws;                                    // [T][H]       8MB
  ushort_t* w1T = normed + (size_t)T_DIM * H_DIM;           // [2][2I][H]  16MB
  ushort_t* w2c = w1T + (size_t)2 * 2 * I_DIM * H_DIM;      // [H][KCAT]    8MB
  ushort_t* actb = w2c + (size_t)H_DIM * KCAT;              // [T][KCAT]   32MB

  // prep1: rmsnorm (4096) + w1 transpose (2048) + w2 transpose->concat (1024)
  k_prep1<<<dim3(T_DIM + 2048 + 1024), 256, 0, stream>>>(
      x, scale, w1, w2, normed, w1T, w2c);
  k_gemm1<<<dim3(1024), 256, 0, stream>>>(normed, w1T, b1, actb);
  k_gemm2<<<dim3(512), 128, 0, stream>>>(actb, w2c, x, b2, out);
}

// Round 19
// 144.846 us; speedup vs baseline: 3.4291x; 3.4291x over previous
//
#include <hip/hip_runtime.h>
#include <hip/hip_bf16.h>
#include <stdint.h>

#define T_DIM 4096
#define H_DIM 1024
#define I_DIM 2048
#define KCAT 4096  // concatenated K for gemm2 (2 experts x I_DIM)

typedef __bf16 bf16x8 __attribute__((ext_vector_type(8)));
typedef float f32x4 __attribute__((ext_vector_type(4)));
typedef unsigned short ushort_t;
typedef unsigned short us4 __attribute__((ext_vector_type(4)));
typedef unsigned short us8 __attribute__((ext_vector_type(8)));

__device__ __forceinline__ unsigned short f32_to_bf16(float f) {
  unsigned int u = __float_as_uint(f);
  u += 0x7fffu + ((u >> 16) & 1u);  // RNE
  return (unsigned short)(u >> 16);
}

__device__ __forceinline__ void gload_lds16(const void* g, void* l) {
  __builtin_amdgcn_global_load_lds(
      (__attribute__((address_space(1))) void*)(uintptr_t)g,
      (__attribute__((address_space(3))) void*)(unsigned int)(uintptr_t)l,
      16, 0, 0);
}

// XOR swizzle (involution; bits 4-6 ^= bits 7-9 of byte offset). Verified R4:
// SQ_LDS_BANK_CONFLICT 6.29M -> 0. Transparent to adds of multiples of 1024.
__device__ __forceinline__ int swz(int L) { return L ^ (((L >> 7) & 7) << 4); }

#define S_BARRIER() asm volatile("s_barrier" ::: "memory")
#define WAITV(n) asm volatile("s_waitcnt vmcnt(" #n ")" ::: "memory")
#define IRFENCE() asm volatile("" ::: "memory")
#define MFMA16(acc, va, vb) \
  acc = __builtin_amdgcn_mfma_f32_16x16x32_bf16(va, vb, acc, 0, 0, 0)

// ------- 64x64 transpose+convert: src f32 (stride sC) -> dst bf16 (stride dR) --
__device__ __forceinline__ void transpose_body64(const float* __restrict__ src,
                                                 ushort_t* __restrict__ dst,
                                                 int sC, int dR, int bx, int by,
                                                 float (*tile)[65]) {
  const int x0 = bx * 64, y0 = by * 64;
  const int tid = threadIdx.x;
  const int lcol4 = tid & 15, lrow = tid >> 4;
#pragma unroll
  for (int i = 0; i < 4; ++i) {
    const int r = lrow + 16 * i;
    const float4 v = ((const float4*)(src + (size_t)(y0 + r) * sC + x0))[lcol4];
    tile[r][lcol4 * 4 + 0] = v.x;
    tile[r][lcol4 * 4 + 1] = v.y;
    tile[r][lcol4 * 4 + 2] = v.z;
    tile[r][lcol4 * 4 + 3] = v.w;
  }
  __syncthreads();
  const int slotr = tid & 7, lcol = tid >> 3;  // 8 row-octs x 32 cols
#pragma unroll
  for (int i = 0; i < 2; ++i) {
    const int c = lcol + 32 * i;
    us8 o;
#pragma unroll
    for (int j = 0; j < 8; ++j) o[j] = f32_to_bf16(tile[slotr * 8 + j][c]);
    *(us8*)(dst + (size_t)(x0 + c) * dR + y0 + slotr * 8) = o;
  }
}

// ------- prep1: rmsnorm (blocks 0..T) + w1T (next 2048) + w2c (next 1024) ------
__global__ __launch_bounds__(256) void k_prep1(
    const float* __restrict__ x, const float* __restrict__ scale,
    const float* __restrict__ w1, const float* __restrict__ w2,
    ushort_t* __restrict__ normed, ushort_t* __restrict__ w1T,
    ushort_t* __restrict__ w2c) {
  __shared__ __align__(16) float shm[64][65];
  const int bid = blockIdx.x;
  if (bid < T_DIM) {
    const int row = bid, tid = threadIdx.x;
    const float4 v = ((const float4*)(x + (size_t)row * H_DIM))[tid];
    float ss = v.x * v.x + v.y * v.y + v.z * v.z + v.w * v.w;
#pragma unroll
    for (int off = 32; off > 0; off >>= 1) ss += __shfl_xor(ss, off);
    if ((tid & 63) == 0) shm[0][tid >> 6] = ss;
    __syncthreads();
    const float tot = shm[0][0] + shm[0][1] + shm[0][2] + shm[0][3];
    const float inv = rsqrtf(tot * (1.0f / H_DIM) + 1e-5f);
    const float4 sc = ((const float4*)scale)[tid];
    us4 o;
    o.x = f32_to_bf16(v.x * inv * sc.x);
    o.y = f32_to_bf16(v.y * inv * sc.y);
    o.z = f32_to_bf16(v.z * inv * sc.z);
    o.w = f32_to_bf16(v.w * inv * sc.w);
    ((us4*)(normed + (size_t)row * H_DIM))[tid] = o;
  } else if (bid < T_DIM + 2048) {
    // w1 [H][2I] -> w1T [2][2I][H]; grid (2I/64=64, H/64=16, 2) flattened.
    const int t = bid - T_DIM;
    const int e = t >> 10;
    transpose_body64(w1 + (size_t)e * H_DIM * 2 * I_DIM,
                     w1T + (size_t)e * 2 * I_DIM * H_DIM, 2 * I_DIM, H_DIM,
                     t & 63, (t >> 6) & 15, shm);
  } else {
    // w2 [I][H] -> w2c [H][KCAT] (expert e at col offset e*I);
    // grid (H/64=16, I/64=32, 2) flattened.
    const int t = bid - T_DIM - 2048;
    const int e = t >> 9;
    transpose_body64(w2 + (size_t)e * I_DIM * H_DIM, w2c + (size_t)e * I_DIM,
                     H_DIM, KCAT, t & 15, (t >> 4) & 31, shm);
  }
}

// ---------------- GEMM1: 128 x (128g+128l), BK=32, DBUF 48KB -------------------
// launch_bounds(256,2): VGPR budget up to 256 (no spill; R18's (256,3) forced
// an 84-VGPR cap -> 1GB scratch). Co-residency via LDS: floor(160/48)=3
// blocks/CU. Stage-1-ahead dbuf, WAITV(0)+barrier per step.
__global__ __launch_bounds__(256, 2) void k_gemm1(
    const ushort_t* __restrict__ normed, const ushort_t* __restrict__ w1T,
    const float* __restrict__ b1, ushort_t* __restrict__ act) {
  __shared__ __align__(16) ushort_t lds[2][3][4096];  // 48 KiB
  char* const ldsB = (char*)&lds[0][0][0];
  const int tid = threadIdx.x;
  const int wg = ((blockIdx.x & 7) << 7) + (blockIdx.x >> 3);  // XCD swizzle
  const int e = wg >> 9;
  const int rem = wg & 511;
  const int brow = (rem >> 4) * 128;
  const int bcol = (rem & 15) * 128;
  const int lane = tid & 63;
  const int wid = tid >> 6;
  const int wm = wid >> 1, wn = wid & 1;
  const int r16 = lane & 15, kh = lane >> 4;

  const ushort_t* gBase = w1T + ((size_t)e * 2 * I_DIM + bcol) * H_DIM;
  const ushort_t* lBase = w1T + ((size_t)e * 2 * I_DIM + I_DIM + bcol) * H_DIM;

  f32x4 accg[4][4], accl[4][4];
  const f32x4 zf = {0.f, 0.f, 0.f, 0.f};
#pragma unroll
  for (int m = 0; m < 4; ++m)
#pragma unroll
    for (int n = 0; n < 4; ++n) { accg[m][n] = zf; accl[m][n] = zf; }

  const ushort_t* pA[2];
  const ushort_t* pG[2];
  const ushort_t* pL[2];
#pragma unroll
  for (int j = 0; j < 2; ++j) {
    const int u = swz(j * 4096 + tid * 16);
    const int r = u >> 6, c = (u & 63) >> 1;
    pA[j] = normed + (size_t)(brow + r) * H_DIM + c;
    pG[j] = gBase + (size_t)r * H_DIM + c;
    pL[j] = lBase + (size_t)r * H_DIM + c;
  }
  const int ldst0 = (tid & ~63) * 16;

  const int abase = swz((wm * 64 + r16) * 64 + kh * 16);
  const int bbase = 8192 + swz((wn * 64 + r16) * 64 + kh * 16);

  auto stage = [&](int buf) {
#pragma unroll
    for (int j = 0; j < 2; ++j) {
      gload_lds16(pA[j], ldsB + buf * 24576 + j * 4096 + ldst0);
      gload_lds16(pG[j], ldsB + buf * 24576 + 8192 + j * 4096 + ldst0);
      gload_lds16(pL[j], ldsB + buf * 24576 + 16384 + j * 4096 + ldst0);
    }
  };

  bf16x8 a[4], bg[4], bl[4];

#define G1_ADV()                                                              \
  {                                                                           \
    _Pragma("unroll") for (int j = 0; j < 2; ++j) {                           \
      pA[j] += 32; pG[j] += 32; pL[j] += 32;                                  \
    }                                                                         \
  }
#define G1_RD(C)                                                              \
  _Pragma("unroll") for (int m = 0; m < 4; ++m)                               \
      a[m] = *(const bf16x8*)(ldsB + (C) * 24576 + abase + m * 1024);         \
  _Pragma("unroll") for (int n = 0; n < 4; ++n) {                             \
    bg[n] = *(const bf16x8*)(ldsB + (C) * 24576 + bbase + n * 1024);          \
    bl[n] = *(const bf16x8*)(ldsB + (C) * 24576 + bbase + 8192 + n * 1024);   \
  }
#define G1_MFMA()                                                             \
  _Pragma("unroll") for (int m = 0; m < 4; ++m)                               \
      _Pragma("unroll") for (int n = 0; n < 4; ++n) {                         \
    MFMA16(accg[m][n], a[m], bg[n]);                                          \
    MFMA16(accl[m][n], a[m], bl[n]);                                          \
  }
// Step t (reading buf C): read frags, stage t+1 into the other buf, MFMA,
// drain all staging (WAITV(0)), barrier. WAR-safe: buf N's step-(t-1) reads
// completed before the t-1 barrier (compiler lgkmcnt precedes MFMA use).
#define G1_STEP(C, N)                                                         \
  {                                                                           \
    G1_RD(C);                                                                 \
    stage(N);                                                                 \
    __builtin_amdgcn_s_setprio(1);                                            \
    G1_MFMA();                                                                \
    __builtin_amdgcn_s_setprio(0);                                            \
    WAITV(0);                                                                 \
    S_BARRIER();                                                              \
    G1_ADV();                                                                 \
  }

  // Prologue: stage tile 0 into buf0.
  stage(0);
  G1_ADV();
  WAITV(0);
  S_BARRIER();

#pragma unroll 1
  for (int it = 0; it < 15; ++it) {  // steps t=0..29
    G1_STEP(0, 1);
    G1_STEP(1, 0);
  }
  G1_STEP(0, 1);  // t=30, stages t=31 into buf1
  // Tail: t=31 in buf1 (drained by t=30's WAITV(0)+barrier).
  {
    G1_RD(1);
    G1_MFMA();
  }
#undef G1_STEP
#undef G1_MFMA
#undef G1_RD
#undef G1_ADV

  const float* b1e = b1 + (size_t)e * 2 * I_DIM;
#pragma unroll
  for (int m = 0; m < 4; ++m)
#pragma unroll
    for (int n = 0; n < 4; ++n) {
      const int gcol = bcol + wn * 64 + n * 16 + r16;
      const float bgb = b1e[gcol];
      const float blb = b1e[I_DIM + gcol];
#pragma unroll
      for (int rr = 0; rr < 4; ++rr) {
        const int grow = brow + wm * 64 + m * 16 + kh * 4 + rr;
        const float hg = accg[m][n][rr] + bgb;
        const float hl = accl[m][n][rr] + blb;
        const float g = fminf(hg, 7.f);
        const float l = fminf(fmaxf(hl, -7.f), 7.f);
        const float s = 1.f / (1.f + __expf(-1.702f * g));
        const float av = g * s * (l + 1.f);
        act[(size_t)grow * KCAT + e * I_DIM + gcol] = f32_to_bf16(av);
      }
    }
}

// ---------------- GEMM2 (R17-verified): plain GEMM K=4096, 2-wave blocks -------
// Tile 128x64, 128 threads (2 waves), tri-buffer 36KB -> 4 blocks/CU,
// 6 loads/step, stage 2 ahead, WAITV(6)/step. 128 K-steps = 42x3 + 2 tail.
__global__ __launch_bounds__(128, 2) void k_gemm2(
    const ushort_t* __restrict__ act, const ushort_t* __restrict__ w2c,
    const float* __restrict__ x, const float* __restrict__ b2,
    float* __restrict__ out) {
  __shared__ __align__(16) ushort_t lds[3][6144];  // 36 KiB
  char* const ldsB = (char*)&lds[0][0];
  const int tid = threadIdx.x;
  const int wg = ((blockIdx.x & 7) << 6) + (blockIdx.x >> 3);  // XCD swizzle
  const int brow = (wg >> 4) * 128;
  const int bcol = (wg & 15) * 64;
  const int lane = tid & 63;
  const int wm = tid >> 6;
  const int r16 = lane & 15, kh = lane >> 4;

  const ushort_t* aBase = act + (size_t)brow * KCAT;
  const ushort_t* bBase = w2c + (size_t)bcol * KCAT;

  f32x4 acc[4][4];
  const f32x4 zf = {0.f, 0.f, 0.f, 0.f};
#pragma unroll
  for (int m = 0; m < 4; ++m)
#pragma unroll
    for (int n = 0; n < 4; ++n) acc[m][n] = zf;

  const ushort_t* pA[4];
  const ushort_t* pB[2];
#pragma unroll
  for (int j = 0; j < 4; ++j) {
    const int u = swz(j * 2048 + tid * 16);
    pA[j] = aBase + (size_t)(u >> 6) * KCAT + ((u & 63) >> 1);
  }
#pragma unroll
  for (int j = 0; j < 2; ++j) {
    const int u = swz(j * 2048 + tid * 16);
    pB[j] = bBase + (size_t)(u >> 6) * KCAT + ((u & 63) >> 1);
  }
  const int ldst0 = (tid & ~63) * 16;

  const int abase = wm * 4096 + swz(r16 * 64 + kh * 16);
  const int bbase = 8192 + swz(r16 * 64 + kh * 16);

  auto stage = [&](int buf) {
#pragma unroll
    for (int j = 0; j < 4; ++j)
      gload_lds16(pA[j], ldsB + buf * 12288 + j * 2048 + ldst0);
#pragma unroll
    for (int j = 0; j < 2; ++j)
      gload_lds16(pB[j], ldsB + buf * 12288 + 8192 + j * 2048 + ldst0);
  };

  bf16x8 a[4], b[4];

#define G2_ADV()                                                              \
  {                                                                           \
    _Pragma("unroll") for (int j = 0; j < 4; ++j) pA[j] += 32;                \
    _Pragma("unroll") for (int j = 0; j < 2; ++j) pB[j] += 32;                \
  }
#define G2_RD(C)                                                              \
  _Pragma("unroll") for (int m = 0; m < 4; ++m)                               \
      a[m] = *(const bf16x8*)(ldsB + (C) * 12288 + abase + m * 1024);         \
  _Pragma("unroll") for (int n = 0; n < 4; ++n)                               \
      b[n] = *(const bf16x8*)(ldsB + (C) * 12288 + bbase + n * 1024);
#define G2_MFMA()                                                             \
  _Pragma("unroll") for (int m = 0; m < 4; ++m)                               \
      _Pragma("unroll") for (int n = 0; n < 4; ++n)                           \
          MFMA16(acc[m][n], a[m], b[n]);
#define G2_STEP(C, N)                                                         \
  {                                                                           \
    G2_RD(C);                                                                 \
    stage(N);                                                                 \
    __builtin_amdgcn_s_setprio(1);                                            \
    G2_MFMA();                                                                \
    __builtin_amdgcn_s_setprio(0);                                            \
    WAITV(6);                                                                 \
    S_BARRIER();                                                              \
    G2_ADV();                                                                 \
  }

  stage(0); IRFENCE();
  G2_ADV();
  stage(1);
  G2_ADV();
  WAITV(6);
  S_BARRIER();

#pragma unroll 1
  for (int it = 0; it < 42; ++it) {  // steps t=0..125, staging t+2 (<=127)
    G2_STEP(0, 2);
    G2_STEP(1, 0);
    G2_STEP(2, 1);
  }
  // Tail: t=126 (b0), t=127 (b1; in flight).
  {
    G2_RD(0);
    G2_MFMA();
    WAITV(0);
    S_BARRIER();
    G2_RD(1);
    G2_MFMA();
  }
#undef G2_STEP
#undef G2_MFMA
#undef G2_RD
#undef G2_ADV

  // Epilogue: plain stores — out = x + 0.5*acc + 0.5*(b2[0]+b2[1]).
#pragma unroll
  for (int m = 0; m < 4; ++m)
#pragma unroll
    for (int n = 0; n < 4; ++n) {
      const int gcol = bcol + n * 16 + r16;
      const float bb = 0.5f * (b2[gcol] + b2[H_DIM + gcol]);
#pragma unroll
      for (int rr = 0; rr < 4; ++rr) {
        const int grow = brow + wm * 64 + m * 16 + kh * 4 + rr;
        out[(size_t)grow * H_DIM + gcol] =
            x[(size_t)grow * H_DIM + gcol] + 0.5f * acc[m][n][rr] + bb;
      }
    }
}

extern "C" void kernel_launch(void* const* d_in, const int* in_sizes, int n_in,
                              void* d_out, int out_size, void* d_ws, size_t ws_size,
                              hipStream_t stream) {
  const float* x = (const float*)d_in[0];
  const float* scale = (const float*)d_in[1];
  // d_in[2]=gate_kernel, d_in[3]=gate_bias: static routing, logits unused.
  const float* w1 = (const float*)d_in[4];
  const float* b1 = (const float*)d_in[5];
  const float* w2 = (const float*)d_in[6];
  const float* b2 = (const float*)d_in[7];
  float* out = (float*)d_out;

  ushort_t* ws = (ushort_t*)d_ws;
  ushort_t* normed = ws;                                    // [T][H]       8MB
  ushort_t* w1T = normed + (size_t)T_DIM * H_DIM;           // [2][2I][H]  16MB
  ushort_t* w2c = w1T + (size_t)2 * 2 * I_DIM * H_DIM;      // [H][KCAT]    8MB
  ushort_t* actb = w2c + (size_t)H_DIM * KCAT;              // [T][KCAT]   32MB

  // prep1: rmsnorm (4096) + w1 transpose (2048) + w2 transpose->concat (1024)
  k_prep1<<<dim3(T_DIM + 2048 + 1024), 256, 0, stream>>>(
      x, scale, w1, w2, normed, w1T, w2c);
  k_gemm1<<<dim3(1024), 256, 0, stream>>>(normed, w1T, b1, actb);
  k_gemm2<<<dim3(512), 128, 0, stream>>>(actb, w2c, x, b2, out);
}